// Round 1
// baseline (863.507 us; speedup 1.0000x reference)
//
#include <hip/hip_runtime.h>
#include <cmath>

#define BATCH 8
#define KDIM  1024
#define CH    576
#define NHEAD 6
#define HDIM  96

// ---------------------------------------------------------------------------
// Projection GEMM: out[n, co] = sum_ci A[n,ci] * W[co,ci] + bias[co]
// M = B*K = 8192, N = CH = 576, Kred = CH = 576.
// 64x64 tile, TK=16, 256 threads, 4x4 register blocking.
// grid.z selects (x1,Wq,bq,Q) / (x2,Wk,bk,K) / (x2,Wv,bv,V).
// ---------------------------------------------------------------------------
__global__ __launch_bounds__(256) void proj_kernel(
    const float* __restrict__ x1, const float* __restrict__ x2,
    const float* __restrict__ Wq, const float* __restrict__ bq,
    const float* __restrict__ Wk, const float* __restrict__ bk,
    const float* __restrict__ Wv, const float* __restrict__ bv,
    float* __restrict__ qbuf, float* __restrict__ kbuf, float* __restrict__ vbuf)
{
    const int z = blockIdx.z;
    const float* A    = (z == 0) ? x1 : x2;
    const float* W    = (z == 0) ? Wq : (z == 1) ? Wk : Wv;
    const float* bias = (z == 0) ? bq : (z == 1) ? bk : bv;
    float* out        = (z == 0) ? qbuf : (z == 1) ? kbuf : vbuf;

    __shared__ float As[64][17];
    __shared__ float Ws[64][17];

    const int tid = threadIdx.x;
    const int tx = tid & 15, ty = tid >> 4;
    const int nBase = blockIdx.x * 64;
    const int mBase = blockIdx.y * 64;

    float acc[4][4] = {};

    for (int k0 = 0; k0 < CH; k0 += 16) {
        // 64x16 tiles: 1024 elems / 256 threads = 4 each, coalesced along k.
        #pragma unroll
        for (int r = 0; r < 4; ++r) {
            int idx = tid + r * 256;
            int row = idx >> 4, col = idx & 15;
            As[row][col] = A[(size_t)(mBase + row) * CH + k0 + col];
            Ws[row][col] = W[(size_t)(nBase + row) * CH + k0 + col];
        }
        __syncthreads();
        #pragma unroll
        for (int kk = 0; kk < 16; ++kk) {
            float a[4], w[4];
            #pragma unroll
            for (int i = 0; i < 4; ++i) a[i] = As[ty * 4 + i][kk];
            #pragma unroll
            for (int j = 0; j < 4; ++j) w[j] = Ws[tx * 4 + j][kk];
            #pragma unroll
            for (int i = 0; i < 4; ++i)
                #pragma unroll
                for (int j = 0; j < 4; ++j)
                    acc[i][j] += a[i] * w[j];
        }
        __syncthreads();
    }
    #pragma unroll
    for (int i = 0; i < 4; ++i) {
        int m = mBase + ty * 4 + i;
        #pragma unroll
        for (int j = 0; j < 4; ++j) {
            int n = nBase + tx * 4 + j;
            out[(size_t)m * CH + n] = acc[i][j] + bias[n];
        }
    }
}

// ---------------------------------------------------------------------------
// Flash-style attention.
// The reshape [B,K,C]->[B,NH,HD,K] is a raw reinterpret: viewing the
// projection buffer as [B][C][K] row-major, head h row d is row (h*HD+d).
// One workgroup per (b, h, 64-query tile). Streams 64-wide K/V tiles with
// online softmax (no 1/sqrt(d) scaling, matching the reference).
// Output written into the same [B][C][K] view (identity reshape).
// ---------------------------------------------------------------------------
__global__ __launch_bounds__(256) void attn_kernel(
    const float* __restrict__ qbuf, const float* __restrict__ kbuf,
    const float* __restrict__ vbuf, float* __restrict__ out)
{
    const int qt = blockIdx.x;   // 0..15
    const int h  = blockIdx.y;   // 0..5
    const int b  = blockIdx.z;   // 0..7

    const int iBase = qt * 64;
    const size_t baseOff = (size_t)b * KDIM * CH + (size_t)h * HDIM * KDIM;
    const float* Q  = qbuf + baseOff;
    const float* Kp = kbuf + baseOff;
    const float* Vp = vbuf + baseOff;

    __shared__ float Qs[HDIM][65];   // [d][i]
    __shared__ float KVs[HDIM][65];  // [d][j], reused for K then V
    __shared__ float Ss[64][65];     // [i][j] scores -> probabilities
    __shared__ float mS[64], lS[64], aS[64];

    const int tid = threadIdx.x;
    const int tx = tid & 15, ty = tid >> 4;
    const int i0 = ty * 4, j0 = tx * 4;   // S-compute mapping
    const int dy0 = ty * 6, ix0 = tx * 4; // O-accumulator mapping

    // Load Q tile: 96*64 / 256 = 24 per thread, coalesced along i.
    #pragma unroll
    for (int r = 0; r < 24; ++r) {
        int idx = tid + r * 256;
        int d = idx >> 6, i = idx & 63;
        Qs[d][i] = Q[(size_t)d * KDIM + iBase + i];
    }
    if (tid < 64) { mS[tid] = -INFINITY; lS[tid] = 0.f; }

    float O[6][4] = {};

    for (int jt = 0; jt < KDIM; jt += 64) {
        __syncthreads();  // prior iter done with KVs (V) and Ss
        // Load K tile
        #pragma unroll
        for (int r = 0; r < 24; ++r) {
            int idx = tid + r * 256;
            int d = idx >> 6, j = idx & 63;
            KVs[d][j] = Kp[(size_t)d * KDIM + jt + j];
        }
        __syncthreads();  // Q + K ready (and m/l initialized on first iter)

        // S[i][j] = sum_d Q[d][i]*K[d][j]
        {
            float acc[4][4] = {};
            #pragma unroll 4
            for (int d = 0; d < HDIM; ++d) {
                float qv[4], kv[4];
                #pragma unroll
                for (int i = 0; i < 4; ++i) qv[i] = Qs[d][i0 + i];
                #pragma unroll
                for (int j = 0; j < 4; ++j) kv[j] = KVs[d][j0 + j];
                #pragma unroll
                for (int i = 0; i < 4; ++i)
                    #pragma unroll
                    for (int j = 0; j < 4; ++j)
                        acc[i][j] += qv[i] * kv[j];
            }
            #pragma unroll
            for (int i = 0; i < 4; ++i)
                #pragma unroll
                for (int j = 0; j < 4; ++j)
                    Ss[i0 + i][j0 + j] = acc[i][j];
        }
        __syncthreads();  // S done; K no longer needed

        // Load V tile (overwrites K) while one wave does row softmax.
        #pragma unroll
        for (int r = 0; r < 24; ++r) {
            int idx = tid + r * 256;
            int d = idx >> 6, j = idx & 63;
            KVs[d][j] = Vp[(size_t)d * KDIM + jt + j];
        }
        if (tid < 64) {
            const int i = tid;
            float mx = -INFINITY;
            #pragma unroll 8
            for (int j = 0; j < 64; ++j) mx = fmaxf(mx, Ss[i][j]);
            float newm = fmaxf(mS[i], mx);
            float alpha = __expf(mS[i] - newm);
            float s = 0.f;
            #pragma unroll 8
            for (int j = 0; j < 64; ++j) {
                float p = __expf(Ss[i][j] - newm);
                Ss[i][j] = p;
                s += p;
            }
            lS[i] = alpha * lS[i] + s;
            mS[i] = newm;
            aS[i] = alpha;
        }
        __syncthreads();  // V + P + alpha ready

        // O[d][i] = alpha_i*O[d][i] + sum_j V[d][j]*P[i][j]
        float al[4];
        #pragma unroll
        for (int i = 0; i < 4; ++i) al[i] = aS[ix0 + i];
        float sum[6][4] = {};
        #pragma unroll 4
        for (int j = 0; j < 64; ++j) {
            float vv[6], pp[4];
            #pragma unroll
            for (int d = 0; d < 6; ++d) vv[d] = KVs[dy0 + d][j];
            #pragma unroll
            for (int i = 0; i < 4; ++i) pp[i] = Ss[ix0 + i][j];
            #pragma unroll
            for (int d = 0; d < 6; ++d)
                #pragma unroll
                for (int i = 0; i < 4; ++i)
                    sum[d][i] += vv[d] * pp[i];
        }
        #pragma unroll
        for (int d = 0; d < 6; ++d)
            #pragma unroll
            for (int i = 0; i < 4; ++i)
                O[d][i] = al[i] * O[d][i] + sum[d][i];
    }

    // Normalize and write. Output viewed as [B][C][K]: row (h*HD+d), col i.
    float linv[4];
    #pragma unroll
    for (int i = 0; i < 4; ++i) linv[i] = 1.0f / lS[ix0 + i];
    #pragma unroll
    for (int d = 0; d < 6; ++d) {
        int dd = dy0 + d;
        #pragma unroll
        for (int i = 0; i < 4; ++i)
            out[baseOff + (size_t)dd * KDIM + iBase + ix0 + i] = O[d][i] * linv[i];
    }
}

extern "C" void kernel_launch(void* const* d_in, const int* in_sizes, int n_in,
                              void* d_out, int out_size, void* d_ws, size_t ws_size,
                              hipStream_t stream)
{
    const float* x1 = (const float*)d_in[0];
    const float* x2 = (const float*)d_in[1];
    const float* Wq = (const float*)d_in[2];
    const float* bq = (const float*)d_in[3];
    const float* Wk = (const float*)d_in[4];
    const float* bk = (const float*)d_in[5];
    const float* Wv = (const float*)d_in[6];
    const float* bv = (const float*)d_in[7];
    float* out = (float*)d_out;

    const size_t per = (size_t)BATCH * KDIM * CH;   // 4,718,592 floats
    float* qbuf = (float*)d_ws;
    float* kbuf = qbuf + per;
    float* vbuf = kbuf + per;

    dim3 pgrid(CH / 64, (BATCH * KDIM) / 64, 3);    // 9 x 128 x 3
    proj_kernel<<<pgrid, 256, 0, stream>>>(x1, x2, Wq, bq, Wk, bk, Wv, bv,
                                           qbuf, kbuf, vbuf);

    dim3 agrid(KDIM / 64, NHEAD, BATCH);            // 16 x 6 x 8
    attn_kernel<<<agrid, 256, 0, stream>>>(qbuf, kbuf, vbuf, out);
}

// Round 2
// 201.315 us; speedup vs baseline: 4.2893x; 4.2893x over previous
//
#include <hip/hip_runtime.h>
#include <cmath>

#define BATCH 8
#define KDIM  1024
#define CH    576
#define NHEAD 6
#define HDIM  96

typedef _Float16 f16;
typedef f16 f16x4 __attribute__((ext_vector_type(4)));
typedef f16 f16x8 __attribute__((ext_vector_type(8)));
typedef float f32x16 __attribute__((ext_vector_type(16)));

__device__ inline f32x16 zero16() {
    f32x16 z;
#pragma unroll
    for (int r = 0; r < 16; ++r) z[r] = 0.f;
    return z;
}

// ---------------------------------------------------------------------------
// fp32 -> fp16 conversion. blockIdx.y selects segment:
// 0: x1 (4718592), 1: x2, 2: Wq (331776), 3: Wk, 4: Wv. float4-vectorized.
// ---------------------------------------------------------------------------
__global__ __launch_bounds__(256) void convert_kernel(
    const float* __restrict__ x1, const float* __restrict__ x2,
    const float* __restrict__ Wq, const float* __restrict__ Wk,
    const float* __restrict__ Wv,
    f16* __restrict__ x1h, f16* __restrict__ x2h,
    f16* __restrict__ wqh, f16* __restrict__ wkh, f16* __restrict__ wvh)
{
    const int seg = blockIdx.y;
    const float* src = (seg == 0) ? x1 : (seg == 1) ? x2 : (seg == 2) ? Wq
                     : (seg == 3) ? Wk : Wv;
    f16* dst = (seg == 0) ? x1h : (seg == 1) ? x2h : (seg == 2) ? wqh
             : (seg == 3) ? wkh : wvh;
    const int n4 = (seg < 2) ? (BATCH * KDIM * CH / 4) : (CH * CH / 4);
    int idx = blockIdx.x * 256 + threadIdx.x;
    if (idx >= n4) return;
    float4 v = ((const float4*)src)[idx];
    f16x4 h; h[0] = (f16)v.x; h[1] = (f16)v.y; h[2] = (f16)v.z; h[3] = (f16)v.w;
    ((f16x4*)dst)[idx] = h;
}

// ---------------------------------------------------------------------------
// Projection GEMM (fp16 MFMA): out[n][co] = sum_ci A[n][ci]*W[co][ci] + b[co]
// 128(m) x 64(n) tile, BK=32, 4 waves each owning a 32-row m-subtile.
// Output written fp16 in [b][t][c] linear layout (scramble-free reinterpret).
// ---------------------------------------------------------------------------
__global__ __launch_bounds__(256) void proj_kernel(
    const f16* __restrict__ x1h, const f16* __restrict__ x2h,
    const f16* __restrict__ wqh, const f16* __restrict__ wkh,
    const f16* __restrict__ wvh,
    const float* __restrict__ bq, const float* __restrict__ bk,
    const float* __restrict__ bv,
    f16* __restrict__ qf, f16* __restrict__ kf, f16* __restrict__ vf)
{
    const int z = blockIdx.z;
    const f16* A    = (z == 0) ? x1h : x2h;
    const f16* W    = (z == 0) ? wqh : (z == 1) ? wkh : wvh;
    const float* bias = (z == 0) ? bq : (z == 1) ? bk : bv;
    f16* dst        = (z == 0) ? qf : (z == 1) ? kf : vf;

    __shared__ f16 As[128 * 40];   // [m][k], stride 40 (80 B)
    __shared__ f16 Ws[64 * 40];    // [co][k]

    const int tid = threadIdx.x;
    const int lane = tid & 63, w = tid >> 6;
    const int l31 = lane & 31, half = lane >> 5;
    const int nBase = blockIdx.x * 64;
    const int mBase = blockIdx.y * 128;

    f32x16 acc0 = zero16(), acc1 = zero16();

    for (int k0 = 0; k0 < CH; k0 += 32) {
        __syncthreads();
        // stage A: 128 rows x 4 chunks of 8 fp16 = 512 tasks
#pragma unroll
        for (int r = 0; r < 2; ++r) {
            int idx = r * 256 + tid;
            int mm = idx >> 2, sub = idx & 3;
            *(f16x8*)&As[mm * 40 + sub * 8] =
                *(const f16x8*)&A[(size_t)(mBase + mm) * CH + k0 + sub * 8];
        }
        // stage W: 64 rows x 4 chunks = 256 tasks
        {
            int co = tid >> 2, sub = tid & 3;
            *(f16x8*)&Ws[co * 40 + sub * 8] =
                *(const f16x8*)&W[(size_t)(nBase + co) * CH + k0 + sub * 8];
        }
        __syncthreads();
#pragma unroll
        for (int ks = 0; ks < 2; ++ks) {
            f16x8 a  = *(const f16x8*)&As[(32 * w + l31) * 40 + 16 * ks + 8 * half];
            f16x8 b0 = *(const f16x8*)&Ws[(l31) * 40 + 16 * ks + 8 * half];
            f16x8 b1 = *(const f16x8*)&Ws[(32 + l31) * 40 + 16 * ks + 8 * half];
            acc0 = __builtin_amdgcn_mfma_f32_32x32x16_f16(a, b0, acc0, 0, 0, 0);
            acc1 = __builtin_amdgcn_mfma_f32_32x32x16_f16(a, b1, acc1, 0, 0, 0);
        }
    }
    // epilogue: C layout col = l31 (n), row = (r&3)+8*(r>>2)+4*half (m)
#pragma unroll
    for (int nt = 0; nt < 2; ++nt) {
        int n = nBase + 32 * nt + l31;
        float bv = bias[n];
        const f32x16& acc = nt ? acc1 : acc0;
#pragma unroll
        for (int r = 0; r < 16; ++r) {
            int m = mBase + 32 * w + (r & 3) + 8 * (r >> 2) + 4 * half;
            dst[(size_t)m * CH + n] = (f16)(acc[r] + bv);
        }
    }
}

// ---------------------------------------------------------------------------
// Transpose Q,K from [bh][d(96)][t(1024)] to [bh][t][d] (fp16) so attention
// fragments are d-contiguous. blockIdx.z: 0=Q, 1=K.
// ---------------------------------------------------------------------------
__global__ __launch_bounds__(256) void transpose_qk(
    const f16* __restrict__ qf, const f16* __restrict__ kf,
    f16* __restrict__ QT, f16* __restrict__ KT)
{
    const int tt = blockIdx.x;   // 16 t-tiles of 64
    const int bh = blockIdx.y;   // 48
    const f16* src = blockIdx.z ? kf : qf;
    f16* dst = blockIdx.z ? KT : QT;

    __shared__ f16 Ts[96 * 72];  // [d][t], stride 72

    const int tid = threadIdx.x;
    const int rowbase = (bh / NHEAD) * CH + (bh % NHEAD) * HDIM;

#pragma unroll
    for (int r = 0; r < 3; ++r) {
        int idx = r * 256 + tid;
        int d = idx >> 3, g = idx & 7;
        *(f16x8*)&Ts[d * 72 + g * 8] =
            *(const f16x8*)&src[(size_t)(rowbase + d) * KDIM + tt * 64 + g * 8];
    }
    __syncthreads();
#pragma unroll
    for (int r = 0; r < 3; ++r) {
        int idx = r * 256 + tid;
        int t = idx & 63, dg = idx >> 6;   // dg in [0,12)
        f16x8 v;
#pragma unroll
        for (int u = 0; u < 8; ++u) v[u] = Ts[(dg * 8 + u) * 72 + t];
        *(f16x8*)&dst[((size_t)bh * KDIM + tt * 64 + t) * HDIM + dg * 8] = v;
    }
}

// ---------------------------------------------------------------------------
// Flash attention, fp16 MFMA 32x32x16.
// Per wg: 128 queries (4 waves x 32), stream 64-key tiles.
// S computed transposed (rows=j keys, cols=i queries) so softmax-over-j is
// per-lane (16 regs x 2 tiles) + one cross-half shuffle.
// P round-trips through LDS (wave-private rows) into B-operand layout.
// LDS: Qs[128][96] + union(Ks[64][104] | Ps[128][72]) + Vs[96][72] = 56.8 KB.
// ---------------------------------------------------------------------------
__global__ __launch_bounds__(256, 2) void attn_kernel(
    const f16* __restrict__ QT, const f16* __restrict__ KT,
    const f16* __restrict__ vf, float* __restrict__ out)
{
    const int qt = blockIdx.x;   // 8 query tiles of 128
    const int h  = blockIdx.y;
    const int b  = blockIdx.z;
    const int bh = b * NHEAD + h;

    __shared__ f16 Qs[128 * 96];
    __shared__ f16 KPs[128 * 72];          // union: Ks[64*104] | Ps[128*72]
    __shared__ f16 Vs[96 * 72];
    f16* Ks = KPs;
    f16* Ps = KPs;

    const int tid = threadIdx.x;
    const int lane = tid & 63, w = tid >> 6;
    const int l31 = lane & 31, half = lane >> 5;
    const int iw = 32 * w;

    const f16* Qbase = QT + ((size_t)bh * KDIM + qt * 128) * HDIM;
    const f16* Kbase = KT + (size_t)bh * KDIM * HDIM;
    const f16* Vbase = vf + (size_t)(b * CH + h * HDIM) * KDIM;

    // stage Q tile [t][d]: 128*12 = 1536 chunk-tasks
#pragma unroll
    for (int r = 0; r < 6; ++r) {
        int g = 2 * r + (tid >> 7);
        int t = tid & 127;
        *(f16x8*)&Qs[t * 96 + g * 8] = *(const f16x8*)&Qbase[t * 96 + g * 8];
    }

    float m_run = -INFINITY, l_run = 0.f;
    f32x16 O0 = zero16(), O1 = zero16(), O2 = zero16();

    for (int jt = 0; jt < KDIM; jt += 64) {
        __syncthreads();   // prev iter done reading Ks/Ps/Vs
        // stage K [j][d]: 64*12 = 768 tasks
#pragma unroll
        for (int r = 0; r < 3; ++r) {
            int idx = r * 256 + tid;
            int t = idx & 63, g = idx >> 6;
            *(f16x8*)&Ks[t * 104 + g * 8] =
                *(const f16x8*)&Kbase[(size_t)(jt + t) * HDIM + g * 8];
        }
        // stage V [d][j]: 96*8 = 768 tasks
#pragma unroll
        for (int r = 0; r < 3; ++r) {
            int idx = r * 256 + tid;
            int d = idx >> 3, g = idx & 7;
            *(f16x8*)&Vs[d * 72 + g * 8] =
                *(const f16x8*)&Vbase[(size_t)d * KDIM + jt + g * 8];
        }
        __syncthreads();   // staging visible

        // S'[j][i]: A=K (m=j), B=Q (n=i). acc s0: j 0..31, s1: j 32..63
        f32x16 s0 = zero16(), s1 = zero16();
#pragma unroll
        for (int k0 = 0; k0 < HDIM; k0 += 16) {
            f16x8 bqf = *(const f16x8*)&Qs[(iw + l31) * 96 + k0 + 8 * half];
            f16x8 a0  = *(const f16x8*)&Ks[(l31) * 104 + k0 + 8 * half];
            f16x8 a1  = *(const f16x8*)&Ks[(32 + l31) * 104 + k0 + 8 * half];
            s0 = __builtin_amdgcn_mfma_f32_32x32x16_f16(a0, bqf, s0, 0, 0, 0);
            s1 = __builtin_amdgcn_mfma_f32_32x32x16_f16(a1, bqf, s1, 0, 0, 0);
        }

        // online softmax over j (rows): per-lane 32 vals + cross-half shuffle
        float mx = -INFINITY;
#pragma unroll
        for (int r = 0; r < 16; ++r) mx = fmaxf(mx, fmaxf(s0[r], s1[r]));
        mx = fmaxf(mx, __shfl_xor(mx, 32));
        float mnew = fmaxf(m_run, mx);
        float alpha = __expf(m_run - mnew);
        m_run = mnew;
        float sum = 0.f;
        f16x4 p0q[4], p1q[4];
#pragma unroll
        for (int r = 0; r < 16; ++r) {
            float e0 = __expf(s0[r] - mnew);
            float e1 = __expf(s1[r] - mnew);
            sum += e0 + e1;
            p0q[r >> 2][r & 3] = (f16)e0;
            p1q[r >> 2][r & 3] = (f16)e1;
        }
        sum += __shfl_xor(sum, 32);
        l_run = alpha * l_run + sum;

        __syncthreads();   // all waves done reading Ks before P overwrite

        // write P: rows j=(q*8 + 4*half + 0..3) (+32 for p1), col i=iw+l31
#pragma unroll
        for (int q = 0; q < 4; ++q) {
            int j0 = 8 * q + 4 * half;
            *(f16x4*)&Ps[(iw + l31) * 72 + j0]      = p0q[q];
            *(f16x4*)&Ps[(iw + l31) * 72 + 32 + j0] = p1q[q];
        }
#pragma unroll
        for (int r = 0; r < 16; ++r) { O0[r] *= alpha; O1[r] *= alpha; O2[r] *= alpha; }

        // PV: D[d][i] = sum_j V[d][j] P'[j][i]; A=Vs rows d, B=Ps
#pragma unroll
        for (int kc = 0; kc < 4; ++kc) {
            f16x8 bp = *(const f16x8*)&Ps[(iw + l31) * 72 + 16 * kc + 8 * half];
            f16x8 a0 = *(const f16x8*)&Vs[(l31) * 72 + 16 * kc + 8 * half];
            f16x8 a1 = *(const f16x8*)&Vs[(32 + l31) * 72 + 16 * kc + 8 * half];
            f16x8 a2 = *(const f16x8*)&Vs[(64 + l31) * 72 + 16 * kc + 8 * half];
            O0 = __builtin_amdgcn_mfma_f32_32x32x16_f16(a0, bp, O0, 0, 0, 0);
            O1 = __builtin_amdgcn_mfma_f32_32x32x16_f16(a1, bp, O1, 0, 0, 0);
            O2 = __builtin_amdgcn_mfma_f32_32x32x16_f16(a2, bp, O2, 0, 0, 0);
        }
    }

    // epilogue: Ctx[d][i]/l -> out viewed [B][C][K]
    float linv = 1.0f / l_run;
    float* obase = out + (size_t)(b * CH + h * HDIM) * KDIM + qt * 128;
    const int i = iw + l31;
#pragma unroll
    for (int r = 0; r < 16; ++r) {
        int row = (r & 3) + 8 * (r >> 2) + 4 * half;
        obase[(size_t)row * KDIM + i]        = O0[r] * linv;
        obase[(size_t)(32 + row) * KDIM + i] = O1[r] * linv;
        obase[(size_t)(64 + row) * KDIM + i] = O2[r] * linv;
    }
}

extern "C" void kernel_launch(void* const* d_in, const int* in_sizes, int n_in,
                              void* d_out, int out_size, void* d_ws, size_t ws_size,
                              hipStream_t stream)
{
    const float* x1 = (const float*)d_in[0];
    const float* x2 = (const float*)d_in[1];
    const float* Wq = (const float*)d_in[2];
    const float* bq = (const float*)d_in[3];
    const float* Wk = (const float*)d_in[4];
    const float* bk = (const float*)d_in[5];
    const float* Wv = (const float*)d_in[6];
    const float* bv = (const float*)d_in[7];
    float* out = (float*)d_out;

    const size_t P = (size_t)BATCH * KDIM * CH;   // 4,718,592
    const size_t WSZ = (size_t)CH * CH;           // 331,776
    f16* x1h = (f16*)d_ws;       // later reused as QT
    f16* x2h = x1h + P;          // later reused as KT
    f16* qf  = x2h + P;
    f16* kf  = qf + P;
    f16* vf  = kf + P;
    f16* wqh = vf + P;
    f16* wkh = wqh + WSZ;
    f16* wvh = wkh + WSZ;
    f16* QT = x1h;
    f16* KT = x2h;

    dim3 cgrid((P / 4 + 255) / 256, 5);
    convert_kernel<<<cgrid, 256, 0, stream>>>(x1, x2, Wq, Wk, Wv,
                                              x1h, x2h, wqh, wkh, wvh);

    dim3 pgrid(CH / 64, (BATCH * KDIM) / 128, 3);   // 9 x 64 x 3
    proj_kernel<<<pgrid, 256, 0, stream>>>(x1h, x2h, wqh, wkh, wvh,
                                           bq, bk, bv, qf, kf, vf);

    dim3 tgrid(KDIM / 64, BATCH * NHEAD, 2);        // 16 x 48 x 2
    transpose_qk<<<tgrid, 256, 0, stream>>>(qf, kf, QT, KT);

    dim3 agrid(KDIM / 128, NHEAD, BATCH);           // 8 x 6 x 8
    attn_kernel<<<agrid, 256, 0, stream>>>(QT, KT, vf, out);
}

// Round 3
// 199.839 us; speedup vs baseline: 4.3210x; 1.0074x over previous
//
#include <hip/hip_runtime.h>
#include <cmath>

#define BATCH 8
#define KDIM  1024
#define CH    576
#define NHEAD 6
#define HDIM  96

typedef _Float16 f16;
typedef f16 f16x4 __attribute__((ext_vector_type(4)));
typedef f16 f16x8 __attribute__((ext_vector_type(8)));
typedef float f32x16 __attribute__((ext_vector_type(16)));

__device__ inline f32x16 zero16() {
    f32x16 z;
#pragma unroll
    for (int r = 0; r < 16; ++r) z[r] = 0.f;
    return z;
}

// ---------------------------------------------------------------------------
// Projection GEMM with fused fp32->fp16 convert.
// out[m][n] = sum_k A[m][k]*W[n][k] + bias[n], M=8192, N=K=576.
// 128x64 tile, BK=64, 4 waves (each a 32-row m-subtile), MFMA 32x32x16.
// Output fp16 in [b][t][c] linear layout == scramble-free [b][c'][t'] view.
// ---------------------------------------------------------------------------
__global__ __launch_bounds__(256) void proj_kernel(
    const float* __restrict__ x1, const float* __restrict__ x2,
    const float* __restrict__ Wq, const float* __restrict__ Wk,
    const float* __restrict__ Wv,
    const float* __restrict__ bq, const float* __restrict__ bk,
    const float* __restrict__ bv,
    f16* __restrict__ qf, f16* __restrict__ kf, f16* __restrict__ vf)
{
    const int z = blockIdx.z;
    const float* A    = (z == 0) ? x1 : x2;
    const float* W    = (z == 0) ? Wq : (z == 1) ? Wk : Wv;
    const float* bias = (z == 0) ? bq : (z == 1) ? bk : bv;
    f16* dst          = (z == 0) ? qf : (z == 1) ? kf : vf;

    __shared__ f16 As[128 * 72];   // stride 72 f16 = 144 B == 4 words mod 32: conflict-free b128
    __shared__ f16 Ws[64 * 72];

    const int tid = threadIdx.x;
    const int lane = tid & 63, w = tid >> 6;
    const int l31 = lane & 31, half = lane >> 5;
    const int nBase = blockIdx.x * 64;
    const int mBase = blockIdx.y * 128;

    f32x16 acc0 = zero16(), acc1 = zero16();

    for (int k0 = 0; k0 < CH; k0 += 64) {
        __syncthreads();
        // A: 128 rows x 8 chunks(8 f16) = 1024 tasks, 4/thread; cvt fp32->fp16
#pragma unroll
        for (int r = 0; r < 4; ++r) {
            int idx = r * 256 + tid;
            int row = idx >> 3, ch = idx & 7;
            const float* src = &A[(size_t)(mBase + row) * CH + k0 + ch * 8];
            float4 u0 = *(const float4*)src;
            float4 u1 = *(const float4*)(src + 4);
            f16x8 hv;
            hv[0] = (f16)u0.x; hv[1] = (f16)u0.y; hv[2] = (f16)u0.z; hv[3] = (f16)u0.w;
            hv[4] = (f16)u1.x; hv[5] = (f16)u1.y; hv[6] = (f16)u1.z; hv[7] = (f16)u1.w;
            *(f16x8*)&As[row * 72 + ch * 8] = hv;
        }
        // W: 64 rows x 8 chunks = 512 tasks, 2/thread
#pragma unroll
        for (int r = 0; r < 2; ++r) {
            int idx = r * 256 + tid;
            int row = idx >> 3, ch = idx & 7;
            const float* src = &W[(size_t)(nBase + row) * CH + k0 + ch * 8];
            float4 u0 = *(const float4*)src;
            float4 u1 = *(const float4*)(src + 4);
            f16x8 hv;
            hv[0] = (f16)u0.x; hv[1] = (f16)u0.y; hv[2] = (f16)u0.z; hv[3] = (f16)u0.w;
            hv[4] = (f16)u1.x; hv[5] = (f16)u1.y; hv[6] = (f16)u1.z; hv[7] = (f16)u1.w;
            *(f16x8*)&Ws[row * 72 + ch * 8] = hv;
        }
        __syncthreads();
#pragma unroll
        for (int ks = 0; ks < 4; ++ks) {
            f16x8 a  = *(const f16x8*)&As[(32 * w + l31) * 72 + 16 * ks + 8 * half];
            f16x8 b0 = *(const f16x8*)&Ws[(l31) * 72 + 16 * ks + 8 * half];
            f16x8 b1 = *(const f16x8*)&Ws[(32 + l31) * 72 + 16 * ks + 8 * half];
            acc0 = __builtin_amdgcn_mfma_f32_32x32x16_f16(a, b0, acc0, 0, 0, 0);
            acc1 = __builtin_amdgcn_mfma_f32_32x32x16_f16(a, b1, acc1, 0, 0, 0);
        }
    }
    // C layout: col = l31 (n), row = (r&3)+8*(r>>2)+4*half (m)
#pragma unroll
    for (int nt = 0; nt < 2; ++nt) {
        int n = nBase + 32 * nt + l31;
        float bsv = bias[n];
        const f32x16& acc = nt ? acc1 : acc0;
#pragma unroll
        for (int r = 0; r < 16; ++r) {
            int m = mBase + 32 * w + (r & 3) + 8 * (r >> 2) + 4 * half;
            dst[(size_t)m * CH + n] = (f16)(acc[r] + bsv);
        }
    }
}

// ---------------------------------------------------------------------------
// Flash attention, no pre-transpose. Q/K staged from native [d][t] layout
// into LDS [t][d] with a 13-chunk rotation swizzle: chunk c of row t stored
// at column ((t+c)%13)*8. Fragment b128 reads are then conflict-free
// (row stride 104 f16 = 208 B == 20 words mod 32).
// 256 threads = 4 waves: (i-half = w&1) x (j-half = w>>1). Each wave runs an
// independent online softmax over its 512-key subset (every other 32-block);
// partials merged once at the end through LDS (log-sum-exp combine).
// ---------------------------------------------------------------------------
__global__ __launch_bounds__(256, 3) void attn_kernel(
    const f16* __restrict__ qf, const f16* __restrict__ kf,
    const f16* __restrict__ vf, float* __restrict__ out)
{
    __shared__ __align__(16) char smem[49664];
    f16* Qs = (f16*)smem;              // 64 x 104, swizzled [t][d]
    f16* Ks = (f16*)(smem + 13312);    // 64 x 104, swizzled [t][d]
    f16* Ps = (f16*)(smem + 26624);    // 64 x 72, [i][j] (wave-private rows/cols)
    f16* Vs = (f16*)(smem + 35840);    // 96 x 72, [d][j]

    const int qt = blockIdx.x;   // 16 query tiles of 64
    const int h  = blockIdx.y;
    const int b  = blockIdx.z;

    const int tid = threadIdx.x;
    const int lane = tid & 63, w = tid >> 6;
    const int ih = w & 1, jg = w >> 1;
    const int l31 = lane & 31, half = lane >> 5;
    const int iw = 32 * ih;

    const size_t headoff = ((size_t)b * CH + (size_t)h * HDIM) * KDIM;
    const f16* Qbase = qf + headoff + qt * 64;
    const f16* Kbase = kf + headoff;
    const f16* Vbase = vf + headoff;

    // stage Q: 96 d-rows x 8 t-chunks = 768 tasks, coalesced reads,
    // swizzled u16 transpose writes.
#pragma unroll
    for (int r = 0; r < 3; ++r) {
        int idx = r * 256 + tid;
        int d = idx >> 3, g = idx & 7;
        f16x8 v = *(const f16x8*)&Qbase[(size_t)d * KDIM + g * 8];
        int c = d >> 3, dl = d & 7;
#pragma unroll
        for (int u = 0; u < 8; ++u) {
            int t = g * 8 + u;
            Qs[t * 104 + ((t + c) % 13) * 8 + dl] = v[u];
        }
    }
    __syncthreads();

    // hoist Q fragments: 6 chunks (ks 0..5), c = 2*ks + half
    f16x8 qfr[6];
#pragma unroll
    for (int ks = 0; ks < 6; ++ks) {
        int t = iw + l31, c = 2 * ks + half;
        qfr[ks] = *(const f16x8*)&Qs[t * 104 + ((t + c) % 13) * 8];
    }

    float m_run = -INFINITY, l_run = 0.f;
    f32x16 Oacc[3] = {zero16(), zero16(), zero16()};

    for (int jt = 0; jt < KDIM; jt += 64) {
        __syncthreads();   // prev tile's Ks/Vs reads done
        // stage K: like Q, rows jt..jt+63
#pragma unroll
        for (int r = 0; r < 3; ++r) {
            int idx = r * 256 + tid;
            int d = idx >> 3, g = idx & 7;
            f16x8 v = *(const f16x8*)&Kbase[(size_t)d * KDIM + jt + g * 8];
            int c = d >> 3, dl = d & 7;
#pragma unroll
            for (int u = 0; u < 8; ++u) {
                int t = g * 8 + u;
                Ks[t * 104 + ((t + c) % 13) * 8 + dl] = v[u];
            }
        }
        // stage V [d][j]: natural layout, b128 writes
#pragma unroll
        for (int r = 0; r < 3; ++r) {
            int idx = r * 256 + tid;
            int d = idx >> 3, g = idx & 7;
            *(f16x8*)&Vs[d * 72 + g * 8] =
                *(const f16x8*)&Vbase[(size_t)d * KDIM + jt + g * 8];
        }
        __syncthreads();

        // S'[j][i] for wave's 32-j block: A=K rows (32*jg + l31), B=Q
        f32x16 s0 = zero16();
#pragma unroll
        for (int ks = 0; ks < 6; ++ks) {
            int t = 32 * jg + l31, c = 2 * ks + half;
            f16x8 ak = *(const f16x8*)&Ks[t * 104 + ((t + c) % 13) * 8];
            s0 = __builtin_amdgcn_mfma_f32_32x32x16_f16(ak, qfr[ks], s0, 0, 0, 0);
        }

        // online softmax over this wave's 32 j (16 per lane + cross-half shfl)
        float mx = -INFINITY;
#pragma unroll
        for (int r = 0; r < 16; ++r) mx = fmaxf(mx, s0[r]);
        mx = fmaxf(mx, __shfl_xor(mx, 32));
        float mnew = fmaxf(m_run, mx);
        float alpha = __expf(m_run - mnew);
        m_run = mnew;
        float sum = 0.f;
        f16x4 pq[4];
#pragma unroll
        for (int r = 0; r < 16; ++r) {
            float e = __expf(s0[r] - mnew);
            sum += e;
            pq[r >> 2][r & 3] = (f16)e;
        }
        sum += __shfl_xor(sum, 32);
        l_run = alpha * l_run + sum;

        // P write (wave-private rows iw..iw+31, cols 32*jg..+31): no barrier
#pragma unroll
        for (int q = 0; q < 4; ++q)
            *(f16x4*)&Ps[(iw + l31) * 72 + 32 * jg + 8 * q + 4 * half] = pq[q];

        if (__any(alpha != 1.0f)) {
#pragma unroll
            for (int t = 0; t < 3; ++t)
#pragma unroll
                for (int r = 0; r < 16; ++r) Oacc[t][r] *= alpha;
        }

        // PV: O[d][i] += sum_{j in wave's 32} V[d][j] * P[i][j]
#pragma unroll
        for (int kc = 0; kc < 2; ++kc) {
            int jo = 32 * jg + 16 * kc + 8 * half;
            f16x8 bp = *(const f16x8*)&Ps[(iw + l31) * 72 + jo];
#pragma unroll
            for (int t = 0; t < 3; ++t) {
                f16x8 av = *(const f16x8*)&Vs[(32 * t + l31) * 72 + jo];
                Oacc[t] = __builtin_amdgcn_mfma_f32_32x32x16_f16(av, bp, Oacc[t], 0, 0, 0);
            }
        }
    }

    // merge the two j-half partials (log-sum-exp combine) via LDS
    __syncthreads();
    float* Oscr = (float*)smem;               // [ih][96][33] fp32 = 25,344 B
    float* mScr = (float*)(smem + 26624);     // [64]
    float* lScr = (float*)(smem + 26880);     // [64]
    if (jg == 1) {
        if (half == 0) { mScr[iw + l31] = m_run; lScr[iw + l31] = l_run; }
        float* od = Oscr + ih * 3168;
#pragma unroll
        for (int t = 0; t < 3; ++t)
#pragma unroll
            for (int r = 0; r < 16; ++r) {
                int d = 32 * t + (r & 3) + 8 * (r >> 2) + 4 * half;
                od[d * 33 + l31] = Oacc[t][r];
            }
    }
    __syncthreads();
    if (jg == 0) {
        float m1 = mScr[iw + l31], l1 = lScr[iw + l31];
        float mstar = fmaxf(m_run, m1);
        float a0 = __expf(m_run - mstar), a1 = __expf(m1 - mstar);
        float linv = 1.0f / (l_run * a0 + l1 * a1);
        const float* od = Oscr + ih * 3168;
        float* obase = out + headoff + qt * 64 + iw + l31;
#pragma unroll
        for (int t = 0; t < 3; ++t)
#pragma unroll
            for (int r = 0; r < 16; ++r) {
                int d = 32 * t + (r & 3) + 8 * (r >> 2) + 4 * half;
                obase[(size_t)d * KDIM] =
                    (Oacc[t][r] * a0 + od[d * 33 + l31] * a1) * linv;
            }
    }
}

extern "C" void kernel_launch(void* const* d_in, const int* in_sizes, int n_in,
                              void* d_out, int out_size, void* d_ws, size_t ws_size,
                              hipStream_t stream)
{
    const float* x1 = (const float*)d_in[0];
    const float* x2 = (const float*)d_in[1];
    const float* Wq = (const float*)d_in[2];
    const float* bq = (const float*)d_in[3];
    const float* Wk = (const float*)d_in[4];
    const float* bk = (const float*)d_in[5];
    const float* Wv = (const float*)d_in[6];
    const float* bv = (const float*)d_in[7];
    float* out = (float*)d_out;

    const size_t P = (size_t)BATCH * KDIM * CH;   // 4,718,592
    f16* qf = (f16*)d_ws;
    f16* kf = qf + P;
    f16* vf = kf + P;

    dim3 pgrid(CH / 64, (BATCH * KDIM) / 128, 3);   // 9 x 64 x 3
    proj_kernel<<<pgrid, 256, 0, stream>>>(x1, x2, Wq, Wk, Wv,
                                           bq, bk, bv, qf, kf, vf);

    dim3 agrid(KDIM / 64, NHEAD, BATCH);            // 16 x 6 x 8
    attn_kernel<<<agrid, 256, 0, stream>>>(qf, kf, vf, out);
}

// Round 5
// 182.417 us; speedup vs baseline: 4.7337x; 1.0955x over previous
//
#include <hip/hip_runtime.h>
#include <cmath>

#define BATCH 8
#define KDIM  1024
#define CH    576
#define NHEAD 6
#define HDIM  96

typedef _Float16 f16;
typedef f16 f16x4 __attribute__((ext_vector_type(4)));
typedef f16 f16x8 __attribute__((ext_vector_type(8)));
typedef float f32x16 __attribute__((ext_vector_type(16)));

__device__ inline f32x16 zero16() {
    f32x16 z;
#pragma unroll
    for (int r = 0; r < 16; ++r) z[r] = 0.f;
    return z;
}

// ---------------------------------------------------------------------------
// Projection GEMM, fused fp32->fp16 convert, 128(m) x 192(n) tile, BK=64.
// out = A @ W^T + b, written FLAT [m][n] fp16 (coalesced). The torch .view
// scramble is a flat reinterpret — handled downstream, NOT a (t,c) transpose.
// ---------------------------------------------------------------------------
__global__ __launch_bounds__(256) void proj_kernel(
    const float* __restrict__ x1, const float* __restrict__ x2,
    const float* __restrict__ Wq, const float* __restrict__ Wk,
    const float* __restrict__ Wv,
    const float* __restrict__ bq, const float* __restrict__ bk,
    const float* __restrict__ bv,
    f16* __restrict__ qf, f16* __restrict__ kf, f16* __restrict__ vf)
{
    const int z = blockIdx.z;
    const float* A    = (z == 0) ? x1 : x2;
    const float* W    = (z == 0) ? Wq : (z == 1) ? Wk : Wv;
    const float* bias = (z == 0) ? bq : (z == 1) ? bk : bv;
    f16* dst          = (z == 0) ? qf : (z == 1) ? kf : vf;

    __shared__ f16 As[128 * 72];   // stride 72 f16 = 36 words ≡ 4 mod 32: conflict-free b128
    __shared__ f16 Ws[192 * 72];

    const int tid = threadIdx.x;
    const int lane = tid & 63, w = tid >> 6;
    const int l31 = lane & 31, half = lane >> 5;
    const int nBase = blockIdx.x * 192;
    const int mBase = blockIdx.y * 128;

    f32x16 acc[6] = {zero16(), zero16(), zero16(), zero16(), zero16(), zero16()};

    for (int k0 = 0; k0 < CH; k0 += 64) {
        __syncthreads();
        // A: 128 rows x 8 chunks(8 f16) = 1024 tasks
#pragma unroll
        for (int r = 0; r < 4; ++r) {
            int idx = r * 256 + tid;
            int row = idx >> 3, ch = idx & 7;
            const float* src = &A[(size_t)(mBase + row) * CH + k0 + ch * 8];
            float4 u0 = *(const float4*)src;
            float4 u1 = *(const float4*)(src + 4);
            f16x8 hv;
            hv[0] = (f16)u0.x; hv[1] = (f16)u0.y; hv[2] = (f16)u0.z; hv[3] = (f16)u0.w;
            hv[4] = (f16)u1.x; hv[5] = (f16)u1.y; hv[6] = (f16)u1.z; hv[7] = (f16)u1.w;
            *(f16x8*)&As[row * 72 + ch * 8] = hv;
        }
        // W: 192 rows x 8 chunks = 1536 tasks
#pragma unroll
        for (int r = 0; r < 6; ++r) {
            int idx = r * 256 + tid;
            int row = idx >> 3, ch = idx & 7;
            const float* src = &W[(size_t)(nBase + row) * CH + k0 + ch * 8];
            float4 u0 = *(const float4*)src;
            float4 u1 = *(const float4*)(src + 4);
            f16x8 hv;
            hv[0] = (f16)u0.x; hv[1] = (f16)u0.y; hv[2] = (f16)u0.z; hv[3] = (f16)u0.w;
            hv[4] = (f16)u1.x; hv[5] = (f16)u1.y; hv[6] = (f16)u1.z; hv[7] = (f16)u1.w;
            *(f16x8*)&Ws[row * 72 + ch * 8] = hv;
        }
        __syncthreads();
#pragma unroll
        for (int ks = 0; ks < 4; ++ks) {
            f16x8 a = *(const f16x8*)&As[(32 * w + l31) * 72 + 16 * ks + 8 * half];
#pragma unroll
            for (int nt = 0; nt < 6; ++nt) {
                f16x8 bfr = *(const f16x8*)&Ws[(32 * nt + l31) * 72 + 16 * ks + 8 * half];
                acc[nt] = __builtin_amdgcn_mfma_f32_32x32x16_f16(a, bfr, acc[nt], 0, 0, 0);
            }
        }
    }

    // flat epilogue (coalesced 2-B stores along n across lanes)
#pragma unroll
    for (int nt = 0; nt < 6; ++nt) {
        int n = nBase + 32 * nt + l31;
        float bsv = bias[n];
#pragma unroll
        for (int r = 0; r < 16; ++r) {
            int m = mBase + 32 * w + (r & 3) + 8 * (r >> 2) + 4 * half;
            dst[(size_t)m * CH + n] = (f16)(acc[nt][r] + bsv);
        }
    }
}

// ---------------------------------------------------------------------------
// Transpose Q,K from the flat buffer's head view [bh][d(96)][t(1024)]
// (correct .view reinterpretation: row = (bh/NH)*CH + (bh%NH)*HD + d)
// to [bh][t][d] fp16. Verified correct in round 2. blockIdx.z: 0=Q, 1=K.
// ---------------------------------------------------------------------------
__global__ __launch_bounds__(256) void transpose_qk(
    const f16* __restrict__ qf, const f16* __restrict__ kf,
    f16* __restrict__ QT, f16* __restrict__ KT)
{
    const int tt = blockIdx.x;   // 16 t-tiles of 64
    const int bh = blockIdx.y;   // 48
    const f16* src = blockIdx.z ? kf : qf;
    f16* dst = blockIdx.z ? KT : QT;

    __shared__ f16 Ts[96 * 72];  // [d][t], stride 72

    const int tid = threadIdx.x;
    const int rowbase = (bh / NHEAD) * CH + (bh % NHEAD) * HDIM;

#pragma unroll
    for (int r = 0; r < 3; ++r) {
        int idx = r * 256 + tid;
        int d = idx >> 3, g = idx & 7;
        *(f16x8*)&Ts[d * 72 + g * 8] =
            *(const f16x8*)&src[(size_t)(rowbase + d) * KDIM + tt * 64 + g * 8];
    }
    __syncthreads();
#pragma unroll
    for (int r = 0; r < 3; ++r) {
        int idx = r * 256 + tid;
        int t = idx & 63, dg = idx >> 6;   // dg in [0,12)
        f16x8 v;
#pragma unroll
        for (int u = 0; u < 8; ++u) v[u] = Ts[(dg * 8 + u) * 72 + t];
        *(f16x8*)&dst[((size_t)bh * KDIM + tt * 64 + t) * HDIM + dg * 8] = v;
    }
}

// ---------------------------------------------------------------------------
// Flash attention. Q,K pre-transposed [bh][t][d]; V via flat [B][C][K] view.
// 64-query tile per block, 4 waves as (i-half)x(j-half); each wave runs an
// independent online softmax over its 512-key subset; merged once at end.
// All staging b128 coalesced; LDS strides 104/72 conflict-free.
// ---------------------------------------------------------------------------
__global__ __launch_bounds__(256, 3) void attn_kernel(
    const f16* __restrict__ qT, const f16* __restrict__ kT,
    const f16* __restrict__ vf, float* __restrict__ out)
{
    __shared__ __align__(16) char smem[49664];
    f16* Qs = (f16*)smem;              // 64 x 104  [t][d]
    f16* Ks = (f16*)(smem + 13312);    // 64 x 104  [t][d]
    f16* Ps = (f16*)(smem + 26624);    // 64 x 72   [i][j]
    f16* Vs = (f16*)(smem + 35840);    // 96 x 72   [d][j]

    const int qt = blockIdx.x;   // 16 query tiles of 64
    const int h  = blockIdx.y;
    const int b  = blockIdx.z;
    const int bh = b * NHEAD + h;

    const int tid = threadIdx.x;
    const int lane = tid & 63, w = tid >> 6;
    const int ih = w & 1, jg = w >> 1;
    const int l31 = lane & 31, half = lane >> 5;
    const int iw = 32 * ih;

    const f16* Qbase = qT + ((size_t)bh * KDIM + qt * 64) * HDIM;
    const f16* Kbase = kT + (size_t)bh * KDIM * HDIM;
    const f16* Vbase = vf + ((size_t)b * CH + (size_t)h * HDIM) * KDIM;

    // stage Q: 64 rows x 12 chunks = 768 tasks, g fastest for coalescing
#pragma unroll
    for (int r = 0; r < 3; ++r) {
        int idx = r * 256 + tid;
        int t = idx / 12, g = idx % 12;
        *(f16x8*)&Qs[t * 104 + g * 8] = *(const f16x8*)&Qbase[t * 96 + g * 8];
    }
    __syncthreads();

    // hoist Q fragments (B-operand: col i = iw+l31, k chunks over d)
    f16x8 qfr[6];
#pragma unroll
    for (int ks = 0; ks < 6; ++ks)
        qfr[ks] = *(const f16x8*)&Qs[(iw + l31) * 104 + 16 * ks + 8 * half];

    float m_run = -INFINITY, l_run = 0.f;
    f32x16 Oacc[3] = {zero16(), zero16(), zero16()};

    for (int jt = 0; jt < KDIM; jt += 64) {
        __syncthreads();
        // stage K rows jt..jt+63
#pragma unroll
        for (int r = 0; r < 3; ++r) {
            int idx = r * 256 + tid;
            int t = idx / 12, g = idx % 12;
            *(f16x8*)&Ks[t * 104 + g * 8] =
                *(const f16x8*)&Kbase[(size_t)(jt + t) * HDIM + g * 8];
        }
        // stage V [d][j]
#pragma unroll
        for (int r = 0; r < 3; ++r) {
            int idx = r * 256 + tid;
            int d = idx >> 3, g = idx & 7;
            *(f16x8*)&Vs[d * 72 + g * 8] =
                *(const f16x8*)&Vbase[(size_t)d * KDIM + jt + g * 8];
        }
        __syncthreads();

        // S'[j][i] for this wave's 32-j block: A = K rows (32*jg + l31)
        f32x16 s0 = zero16();
#pragma unroll
        for (int ks = 0; ks < 6; ++ks) {
            f16x8 ak = *(const f16x8*)&Ks[(32 * jg + l31) * 104 + 16 * ks + 8 * half];
            s0 = __builtin_amdgcn_mfma_f32_32x32x16_f16(ak, qfr[ks], s0, 0, 0, 0);
        }

        // wave-private online softmax over 32 j (16/lane + cross-half shfl)
        float mx = -INFINITY;
#pragma unroll
        for (int r = 0; r < 16; ++r) mx = fmaxf(mx, s0[r]);
        mx = fmaxf(mx, __shfl_xor(mx, 32));
        float mnew = fmaxf(m_run, mx);
        float alpha = __expf(m_run - mnew);
        m_run = mnew;
        float sum = 0.f;
        f16x4 pq[4];
#pragma unroll
        for (int r = 0; r < 16; ++r) {
            float e = __expf(s0[r] - mnew);
            sum += e;
            pq[r >> 2][r & 3] = (f16)e;
        }
        sum += __shfl_xor(sum, 32);
        l_run = alpha * l_run + sum;

        // P write: wave-private rows/cols, no barrier needed
#pragma unroll
        for (int q = 0; q < 4; ++q)
            *(f16x4*)&Ps[(iw + l31) * 72 + 32 * jg + 8 * q + 4 * half] = pq[q];

        if (__any(alpha != 1.0f)) {
#pragma unroll
            for (int t = 0; t < 3; ++t)
#pragma unroll
                for (int r = 0; r < 16; ++r) Oacc[t][r] *= alpha;
        }

        // PV: O[d][i] += sum_{j in wave's 32} V[d][j] * P[i][j]
#pragma unroll
        for (int kc = 0; kc < 2; ++kc) {
            int jo = 32 * jg + 16 * kc + 8 * half;
            f16x8 bp = *(const f16x8*)&Ps[(iw + l31) * 72 + jo];
#pragma unroll
            for (int t = 0; t < 3; ++t) {
                f16x8 av = *(const f16x8*)&Vs[(32 * t + l31) * 72 + jo];
                Oacc[t] = __builtin_amdgcn_mfma_f32_32x32x16_f16(av, bp, Oacc[t], 0, 0, 0);
            }
        }
    }

    // merge the two j-half partials (log-sum-exp) via LDS
    __syncthreads();
    float* Oscr = (float*)smem;               // [ih][96][33] fp32
    float* mScr = (float*)(smem + 26624);
    float* lScr = (float*)(smem + 26880);
    if (jg == 1) {
        if (half == 0) { mScr[iw + l31] = m_run; lScr[iw + l31] = l_run; }
        float* od = Oscr + ih * 3168;
#pragma unroll
        for (int t = 0; t < 3; ++t)
#pragma unroll
            for (int r = 0; r < 16; ++r) {
                int d = 32 * t + (r & 3) + 8 * (r >> 2) + 4 * half;
                od[d * 33 + l31] = Oacc[t][r];
            }
    }
    __syncthreads();
    if (jg == 0) {
        float m1 = mScr[iw + l31], l1 = lScr[iw + l31];
        float mstar = fmaxf(m_run, m1);
        float a0 = __expf(m_run - mstar), a1 = __expf(m1 - mstar);
        float linv = 1.0f / (l_run * a0 + l1 * a1);
        const float* od = Oscr + ih * 3168;
        float* obase = out + ((size_t)b * CH + (size_t)h * HDIM) * KDIM
                           + qt * 64 + iw + l31;
#pragma unroll
        for (int t = 0; t < 3; ++t)
#pragma unroll
            for (int r = 0; r < 16; ++r) {
                int d = 32 * t + (r & 3) + 8 * (r >> 2) + 4 * half;
                obase[(size_t)d * KDIM] =
                    (Oacc[t][r] * a0 + od[d * 33 + l31] * a1) * linv;
            }
    }
}

extern "C" void kernel_launch(void* const* d_in, const int* in_sizes, int n_in,
                              void* d_out, int out_size, void* d_ws, size_t ws_size,
                              hipStream_t stream)
{
    const float* x1 = (const float*)d_in[0];
    const float* x2 = (const float*)d_in[1];
    const float* Wq = (const float*)d_in[2];
    const float* bq = (const float*)d_in[3];
    const float* Wk = (const float*)d_in[4];
    const float* bk = (const float*)d_in[5];
    const float* Wv = (const float*)d_in[6];
    const float* bv = (const float*)d_in[7];
    float* out = (float*)d_out;

    const size_t P = (size_t)BATCH * KDIM * CH;   // 4,718,592
    f16* qf = (f16*)d_ws;       // flat [m][n]
    f16* kf = qf + P;
    f16* vf = kf + P;
    f16* QT = vf + P;           // [bh][t][d]
    f16* KT = QT + P;

    dim3 pgrid(CH / 192, (BATCH * KDIM) / 128, 3);  // 3 x 64 x 3
    proj_kernel<<<pgrid, 256, 0, stream>>>(x1, x2, Wq, Wk, Wv,
                                           bq, bk, bv, qf, kf, vf);

    dim3 tgrid(KDIM / 64, BATCH * NHEAD, 2);        // 16 x 48 x 2
    transpose_qk<<<tgrid, 256, 0, stream>>>(qf, kf, QT, KT);

    dim3 agrid(KDIM / 64, NHEAD, BATCH);            // 16 x 6 x 8
    attn_kernel<<<agrid, 256, 0, stream>>>(QT, KT, vf, out);
}